// Round 1
// baseline (1076.429 us; speedup 1.0000x reference)
//
#include <hip/hip_runtime.h>
#include <cmath>

#define V_NODES  1000000
#define NODE_DIM 128
#define HIDDEN   128
#define OUT_DIM  128
#define GDIM     64
#define NGRAPH   50000

typedef unsigned short u16;
typedef __attribute__((ext_vector_type(8))) short          short8;
typedef __attribute__((ext_vector_type(8))) unsigned short ushort8;
typedef __attribute__((ext_vector_type(8))) __bf16         bf16x8;
typedef __attribute__((ext_vector_type(4))) float          f32x4;

__device__ __forceinline__ u16 f2bf(float f) {
  unsigned u = __builtin_bit_cast(unsigned, f);
  u += 0x7fff + ((u >> 16) & 1);   // RTNE
  return (u16)(u >> 16);
}

__device__ __forceinline__ f32x4 mfma_bf16(bf16x8 a, bf16x8 b, f32x4 c) {
  return __builtin_amdgcn_mfma_f32_16x16x32_bf16(a, b, c, 0, 0, 0);
}

// ---------- prep: weights -> bf16 in ws ----------
__global__ __launch_bounds__(256) void convert_weights(
    const float* __restrict__ W1, const float* __restrict__ W2,
    const float* __restrict__ W3,
    u16* __restrict__ w1b, u16* __restrict__ w2b, u16* __restrict__ w3b) {
  int i = blockIdx.x * 256 + threadIdx.x;
  if (i < NODE_DIM * HIDDEN) {
    w1b[i] = f2bf(W1[i]);
    w2b[i] = f2bf(W2[i]);
  }
  if (i < OUT_DIM * (2 * HIDDEN + GDIM)) w3b[i] = f2bf(W3[i]);
}

// ---------- fused gated MLP + segment scatter ----------
// block = 256 threads = 4 waves; each block handles 64 nodes (wave w: 16 rows).
// LDS: W1,W2 bf16, rows of 128 elems, 16B chunks XOR-swizzled by (row&15)
// -> ds_read_b128 at 2-way bank aliasing (free).
__global__ __launch_bounds__(256, 2) void gated_scatter(
    const float* __restrict__ x, const int* __restrict__ n2g,
    const u16* __restrict__ w1b, const u16* __restrict__ w2b,
    const float* __restrict__ b1, const float* __restrict__ b2,
    float* __restrict__ Z1, float* __restrict__ cnt) {
  extern __shared__ u16 lds[];
  u16* sW1 = lds;          // 16384 elems
  u16* sW2 = lds + 16384;  // 16384 elems
  const int tid = threadIdx.x;

  // stage 2x32KB bf16 weights, swizzled
#pragma unroll
  for (int i = 0; i < 8; ++i) {
    int m = i * 256 + tid;               // 16-byte chunk id, 0..2047
    int n = m >> 4, c = m & 15;
    int p = c ^ (n & 15);
    *(ushort8*)(sW1 + n * 128 + p * 8) = *(const ushort8*)(w1b + m * 8);
    *(ushort8*)(sW2 + n * 128 + p * 8) = *(const ushort8*)(w2b + m * 8);
  }
  __syncthreads();

  const int lane = tid & 63;
  const int wv   = tid >> 6;
  const int q    = lane >> 4;   // quad
  const int mr   = lane & 15;
  const int rowbase = blockIdx.x * 64 + wv * 16;
  const int arow    = rowbase + mr;

  f32x4 acc1[8] = {};
  f32x4 acc2[8] = {};

#pragma unroll
  for (int kc = 0; kc < 4; ++kc) {
    const int k0 = kc * 32;
    // A fragment: x[arow][k0 + q*8 + j], fp32 -> bf16
    const float* ap = x + (size_t)arow * NODE_DIM + k0 + q * 8;
    float4 a0 = *(const float4*)ap;
    float4 a1 = *(const float4*)(ap + 4);
    bf16x8 af;
    af[0] = (__bf16)a0.x; af[1] = (__bf16)a0.y; af[2] = (__bf16)a0.z; af[3] = (__bf16)a0.w;
    af[4] = (__bf16)a1.x; af[5] = (__bf16)a1.y; af[6] = (__bf16)a1.z; af[7] = (__bf16)a1.w;

    const int p = ((k0 >> 3) + q) ^ mr;  // swizzled chunk (n&15 == mr)
#pragma unroll
    for (int t = 0; t < 8; ++t) {
      const int n = t * 16 + mr;
      short8 bs1 = *(const short8*)(sW1 + n * 128 + p * 8);
      short8 bs2 = *(const short8*)(sW2 + n * 128 + p * 8);
      acc1[t] = mfma_bf16(af, __builtin_bit_cast(bf16x8, bs1), acc1[t]);
      acc2[t] = mfma_bf16(af, __builtin_bit_cast(bf16x8, bs2), acc2[t]);
    }
  }

  // graph ids for this quad's 4 output rows
  int g[4];
#pragma unroll
  for (int r = 0; r < 4; ++r) g[r] = n2g[rowbase + q * 4 + r];

#pragma unroll
  for (int t = 0; t < 8; ++t) {
    const int col = t * 16 + mr;
    const float bb1 = b1[col];
    const float bb2 = b2[col];
#pragma unroll
    for (int r = 0; r < 4; ++r) {
      float l1 = acc1[t][r] + bb1;
      float l2 = acc2[t][r] + bb2;
      float h  = l1 / (1.0f + __expf(-l2));
      atomicAdd(Z1 + (size_t)g[r] * HIDDEN + col, h);
    }
  }

  if (tid < 64) atomicAdd(cnt + n2g[blockIdx.x * 64 + tid], 1.0f);
}

// ---------- readout: relu([Z1, Z1/cnt, gx] @ W3^T + b3) ----------
__global__ __launch_bounds__(256, 4) void readout_k(
    const float* __restrict__ Z1, const float* __restrict__ cnt,
    const float* __restrict__ gx, const u16* __restrict__ w3b,
    const float* __restrict__ b3, float* __restrict__ out) {
  const int tid  = threadIdx.x;
  const int lane = tid & 63;
  const int wv   = tid >> 6;
  const int q    = lane >> 4;
  const int mr   = lane & 15;
  const int rowbase = blockIdx.x * 64 + wv * 16;
  const int arow    = rowbase + mr;
  const bool rowok  = arow < NGRAPH;   // wave-uniform (NGRAPH % 16 == 0)

  float inv = 0.0f;
  if (rowok) inv = 1.0f / fmaxf(cnt[arow], 1.0f);

  f32x4 acc[8] = {};

#pragma unroll
  for (int kc = 0; kc < 10; ++kc) {
    const int k0 = kc * 32;
    float av[8];
    if (rowok) {
      if (k0 < 128) {
        const float* p = Z1 + (size_t)arow * HIDDEN + k0 + q * 8;
        float4 a0 = *(const float4*)p;
        float4 a1 = *(const float4*)(p + 4);
        av[0]=a0.x; av[1]=a0.y; av[2]=a0.z; av[3]=a0.w;
        av[4]=a1.x; av[5]=a1.y; av[6]=a1.z; av[7]=a1.w;
      } else if (k0 < 256) {
        const float* p = Z1 + (size_t)arow * HIDDEN + (k0 - 128) + q * 8;
        float4 a0 = *(const float4*)p;
        float4 a1 = *(const float4*)(p + 4);
        av[0]=a0.x*inv; av[1]=a0.y*inv; av[2]=a0.z*inv; av[3]=a0.w*inv;
        av[4]=a1.x*inv; av[5]=a1.y*inv; av[6]=a1.z*inv; av[7]=a1.w*inv;
      } else {
        const float* p = gx + (size_t)arow * GDIM + (k0 - 256) + q * 8;
        float4 a0 = *(const float4*)p;
        float4 a1 = *(const float4*)(p + 4);
        av[0]=a0.x; av[1]=a0.y; av[2]=a0.z; av[3]=a0.w;
        av[4]=a1.x; av[5]=a1.y; av[6]=a1.z; av[7]=a1.w;
      }
    } else {
#pragma unroll
      for (int j = 0; j < 8; ++j) av[j] = 0.0f;
    }
    bf16x8 af;
#pragma unroll
    for (int j = 0; j < 8; ++j) af[j] = (__bf16)av[j];

#pragma unroll
    for (int t = 0; t < 8; ++t) {
      const int n = t * 16 + mr;
      short8 bs = *(const short8*)(w3b + (size_t)n * (2 * HIDDEN + GDIM) + k0 + q * 8);
      acc[t] = mfma_bf16(af, __builtin_bit_cast(bf16x8, bs), acc[t]);
    }
  }

#pragma unroll
  for (int t = 0; t < 8; ++t) {
    const int col = t * 16 + mr;
    const float bb = b3[col];
#pragma unroll
    for (int r = 0; r < 4; ++r) {
      const int row = rowbase + q * 4 + r;
      if (row < NGRAPH)
        out[(size_t)row * OUT_DIM + col] = fmaxf(acc[t][r] + bb, 0.0f);
    }
  }
}

extern "C" void kernel_launch(void* const* d_in, const int* in_sizes, int n_in,
                              void* d_out, int out_size, void* d_ws, size_t ws_size,
                              hipStream_t stream) {
  const float* x   = (const float*)d_in[0];
  const int*   n2g = (const int*)d_in[1];
  const float* gx  = (const float*)d_in[2];
  const float* W1  = (const float*)d_in[3];
  const float* b1  = (const float*)d_in[4];
  const float* W2  = (const float*)d_in[5];
  const float* b2  = (const float*)d_in[6];
  const float* W3  = (const float*)d_in[7];
  const float* b3  = (const float*)d_in[8];
  float* out = (float*)d_out;

  // ws layout:
  //   [0,32768)         W1 bf16
  //   [32768,65536)     W2 bf16
  //   [65536,147456)    W3 bf16 (81920 B)
  //   [147456, +25.6MB) Z1 fp32  (NGRAPH*128)
  //   then counts fp32  (NGRAPH)
  char* ws = (char*)d_ws;
  u16*   w1b = (u16*)(ws);
  u16*   w2b = (u16*)(ws + 32768);
  u16*   w3b = (u16*)(ws + 65536);
  float* Z1  = (float*)(ws + 147456);
  float* cnt = (float*)(ws + 147456 + (size_t)NGRAPH * HIDDEN * 4);

  hipMemsetAsync(ws + 147456, 0,
                 (size_t)NGRAPH * HIDDEN * 4 + (size_t)NGRAPH * 4, stream);

  convert_weights<<<160, 256, 0, stream>>>(W1, W2, W3, w1b, w2b, w3b);

  gated_scatter<<<V_NODES / 64, 256, 2 * 16384 * sizeof(u16), stream>>>(
      x, n2g, w1b, w2b, b1, b2, Z1, cnt);

  readout_k<<<(NGRAPH + 63) / 64, 256, 0, stream>>>(Z1, cnt, gx, w3b, b3, out);
}